// Round 3
// baseline (1049.918 us; speedup 1.0000x reference)
//
#include <hip/hip_runtime.h>

typedef _Float16 half8  __attribute__((ext_vector_type(8)));
typedef float    floatx4 __attribute__((ext_vector_type(4)));

#define HW 128

// LDS layout: word(px, cp) = px*20 + (cp ^ 4*((px>>3)&3)), cp = ci-pair 0..15.
// - b128 reads (4 consecutive cp, px-stride-1 lanes): starts {20*px mod 32} = 8
//   distinct -> 2-way (free); XOR key keeps 16B alignment (multiple of 4 words).
// - staging writes (px-stride-4 lanes): 80 = 16 mod 32 would give 2 banks; the
//   (px>>3)&3 key spreads to 8 banks -> 2-way (free).
__device__ __forceinline__ int lds_word(int px, int cp) {
    return px * 20 + (cp ^ (4 * ((px >> 3) & 3)));
}

// Binarize weights -> f16 (+1/-1), layout Wp[b][t][co][ci] (ci contiguous).
__global__ void prep_weights(const float* __restrict__ w1,
                             const float* __restrict__ w2,
                             const float* __restrict__ w3,
                             const float* __restrict__ w4,
                             _Float16* __restrict__ wp)
{
    int idx  = blockIdx.x * 256 + threadIdx.x;   // 0 .. 327679 = 4*5*64*256
    int ci   = idx & 255;
    int rest = idx >> 8;
    int co   = rest & 63;
    int bt   = rest >> 6;                        // 0..19
    int t    = bt % 5;
    int b    = bt / 5;
    const float* w = (b == 0) ? w1 : (b == 1) ? w2 : (b == 2) ? w3 : w4;
    float v = w[(co * 256 + ci) * 5 + t];
    wp[idx] = (v < 0.0f) ? (_Float16)(-1.0f) : (_Float16)(1.0f);
}

// Block: 16w x 8h tile, type = blockIdx.x&1 (0: H branches 0,1; 1: V branches 2,3).
// 4 waves: wave = bi*2 + half; wave computes 64co x 64px (acc[4][4] = 64 AGPR).
// Halo: type0 = 24w x 8h (no h halo), type1 = 16w x 16h (no w halo).
__global__ __launch_bounds__(256, 3)
void bconv_mfma(const float* __restrict__ x,
                const _Float16* __restrict__ wp,
                const float* __restrict__ bb1,
                const float* __restrict__ bb2,
                const float* __restrict__ bb3,
                const float* __restrict__ bb4,
                float* __restrict__ out)
{
    __shared__ __align__(16) unsigned int xs[5120];   // 20480 B
    __shared__ float bias_s[256];

    const int tid  = threadIdx.x;
    const int type = blockIdx.x & 1;
    const int w0   = (blockIdx.x >> 1) * 16;
    const int h0   = blockIdx.y * 8;
    const int nimg = blockIdx.z;

    {   // stage all 256 biases (branch-major) into LDS
        int br = tid >> 6, i = tid & 63;
        const float* bp = (br == 0) ? bb1 : (br == 1) ? bb2 : (br == 2) ? bb3 : bb4;
        bias_s[tid] = bp[i];
    }

    const int lane   = tid & 63;
    const int wave   = tid >> 6;
    const int bi     = wave >> 1;          // branch within type
    const int half   = wave & 1;           // row half (rows 0-3 / 4-7)
    const int branch = type * 2 + bi;      // 0..3 global branch id
    const int dil    = bi + 1;
    const int quad   = lane >> 4;
    const int wl     = lane & 15;

    floatx4 acc[4][4];
    #pragma unroll
    for (int m = 0; m < 4; ++m)
        #pragma unroll
        for (int n = 0; n < 4; ++n)
            acc[m][n] = (floatx4){0.f, 0.f, 0.f, 0.f};

    // ---- staging task geometry (lane order keeps w fastest -> coalesced) ----
    const int NT = type ? 4 : 3;           // tasks per thread per chunk
    int s_px[4], s_cp[4];
    const float* s_ptr[4];
    bool s_ok[4];
    for (int s = 0; s < 4; ++s) {
        int u = s * 256 + tid;
        int f, hh, cp, wg, hg, rowpx;
        if (type == 0) { f = u % 6;  hh = (u / 6) & 7;   cp = u / 48; wg = w0 - 4 + f * 4; hg = h0 + hh;     rowpx = 24; }
        else           { f = u & 3;  hh = (u >> 2) & 15; cp = u >> 6; wg = w0 + f * 4;     hg = h0 - 4 + hh; rowpx = 16; }
        if (cp > 15) cp = 15;  // inactive tasks (s >= NT) – clamp for safe addr
        s_px[s]  = hh * rowpx + f * 4;
        s_cp[s]  = cp;
        s_ok[s]  = (wg >= 0) && (wg <= HW - 4) && (hg >= 0) && (hg < HW);
        s_ptr[s] = x + (((long)(nimg * 256 + cp * 2) * HW + hg) * HW + wg);
    }

    floatx4 R[8];

    // prologue: issue chunk 0 loads
    {
        const int coff = 0;
        for (int s = 0; s < NT; ++s) {
            floatx4 a = {0.f,0.f,0.f,0.f}, b = {0.f,0.f,0.f,0.f};
            if (s_ok[s]) {
                const floatx4* p = (const floatx4*)(s_ptr[s] + coff);
                a = p[0];
                b = p[(HW * HW) / 4];
            }
            R[2 * s] = a; R[2 * s + 1] = b;
        }
    }

    for (int c = 0; c < 8; ++c) {
        __syncthreads();   // previous chunk's LDS reads done
        // commit: cvt f32->f16 pairs, write to swizzled LDS
        for (int s = 0; s < NT; ++s) {
            int base = s_px[s], cp = s_cp[s];
            #pragma unroll
            for (int i = 0; i < 4; ++i)
                xs[lds_word(base + i, cp)] =
                    __builtin_bit_cast(unsigned int,
                        __builtin_amdgcn_cvt_pkrtz(R[2 * s][i], R[2 * s + 1][i]));
        }
        __syncthreads();

        // issue next chunk's loads (overlap with MFMA below)
        if (c < 7) {
            const int coff = (c + 1) * 32 * HW * HW;
            for (int s = 0; s < NT; ++s) {
                floatx4 a = {0.f,0.f,0.f,0.f}, b = {0.f,0.f,0.f,0.f};
                if (s_ok[s]) {
                    const floatx4* p = (const floatx4*)(s_ptr[s] + coff);
                    a = p[0];
                    b = p[(HW * HW) / 4];
                }
                R[2 * s] = a; R[2 * s + 1] = b;
            }
        }

        // compute: 5 taps x 4 co-tiles x 4 rows
        #pragma unroll
        for (int t = 0; t < 5; ++t) {
            half8 B[4];
            #pragma unroll
            for (int n = 0; n < 4; ++n) {
                int row = half * 4 + n;
                int px;
                if (type == 0) px = row * 24 + (wl + 4 + (t - 2) * dil);
                else           px = (row + 4 + (t - 2) * dil) * 16 + wl;
                B[n] = *(const half8*)&xs[lds_word(px, quad * 4)];
            }
            #pragma unroll
            for (int m = 0; m < 4; ++m) {
                half8 A = *(const half8*)(wp +
                    (((branch * 5 + t) * 64 + m * 16 + wl) * 256 + c * 32 + quad * 8));
                #pragma unroll
                for (int n = 0; n < 4; ++n)
                    acc[m][n] = __builtin_amdgcn_mfma_f32_16x16x32_f16(A, B[n], acc[m][n], 0, 0, 0);
            }
        }
    }

    // ---- epilogue: bias + store (D: col=wl -> w, row=quad*4+r -> co) ----
    float bv[4][4];
    #pragma unroll
    for (int m = 0; m < 4; ++m)
        #pragma unroll
        for (int r = 0; r < 4; ++r)
            bv[m][r] = bias_s[branch * 64 + m * 16 + quad * 4 + r];

    #pragma unroll
    for (int m = 0; m < 4; ++m) {
        #pragma unroll
        for (int n = 0; n < 4; ++n) {
            int co = branch * 64 + m * 16 + quad * 4;
            int h  = h0 + half * 4 + n;
            int base = ((nimg * 256 + co) * HW + h) * HW + w0 + wl;
            #pragma unroll
            for (int r = 0; r < 4; ++r)
                out[base + r * HW * HW] = acc[m][n][r] + bv[m][r];
        }
    }
}

extern "C" void kernel_launch(void* const* d_in, const int* in_sizes, int n_in,
                              void* d_out, int out_size, void* d_ws, size_t ws_size,
                              hipStream_t stream)
{
    (void)in_sizes; (void)n_in; (void)out_size; (void)ws_size;
    const float* x  = (const float*)d_in[0];
    const float* w1 = (const float*)d_in[1];
    const float* b1 = (const float*)d_in[2];
    const float* w2 = (const float*)d_in[3];
    const float* b2 = (const float*)d_in[4];
    const float* w3 = (const float*)d_in[5];
    const float* b3 = (const float*)d_in[6];
    const float* w4 = (const float*)d_in[7];
    const float* b4 = (const float*)d_in[8];
    float*    out = (float*)d_out;
    _Float16* wp  = (_Float16*)d_ws;   // 655360 B

    prep_weights<<<1280, 256, 0, stream>>>(w1, w2, w3, w4, wp);

    // grid.x: 8 w-tiles x 2 types interleaved (H/V of same tile adjacent for L2)
    dim3 grid(16, 16, 16);
    bconv_mfma<<<grid, dim3(256), 0, stream>>>(x, wp, b1, b2, b3, b4, out);
}